// Round 4
// baseline (77.414 us; speedup 1.0000x reference)
//
#include <hip/hip_runtime.h>
#include <math.h>

// Problem constants (match reference)
#define Hh 121
#define Ww 121
#define NPI 200          // N_INTERP
#define Bb 8
#define Ee 225
#define NPIX (Hh * Ww)   // 14641
#define TS 16            // pixel tile side
#define XT 8
#define YT 8
#define NTILE (XT * YT)  // 64 tiles per batch
#define SLOTS 228        // 225 survivors max, rounded up to multiple of 4

#define RPD      280.0f
#define XLOWc   (-4200.0f)
#define RSTEP   (199.0f / 8400.0f)       // 1/STEP
#define ODXc     4340.0f
#define PIc      3.14159265358979323846f
#define INV2PI   0.15915494309189535f    // 1/(2*pi) (v_sin/v_cos take revolutions)
#define INV4PI   0.07957747154594767f    // 1/(4*pi)
#define NHL     (-0.72134752044448170368f)  // -0.5 * log2(e)
#define CULL_T   20.0f   // drop terms provably < bright * 2^-20
#define NL2_045  1.15200309344504995f    // -log2(0.45)

#if __has_builtin(__builtin_amdgcn_exp2f)
#define EXP2F(x) __builtin_amdgcn_exp2f(x)
#else
#define EXP2F(x) exp2f(x)
#endif
#if __has_builtin(__builtin_amdgcn_logf)
#define LOG2F(x) __builtin_amdgcn_logf(x)
#else
#define LOG2F(x) log2f(x)
#endif
#if __has_builtin(__builtin_amdgcn_sinf)
#define SINR(x) __builtin_amdgcn_sinf((x) * INV2PI)   // sin(x), x in radians
#define COSR(x) __builtin_amdgcn_cosf((x) * INV2PI)
#else
#define SINR(x) sinf(x)
#define COSR(x) cosf(x)
#endif
#if __has_builtin(__builtin_amdgcn_rcpf)
#define RCPF(x) __builtin_amdgcn_rcpf(x)
#else
#define RCPF(x) (1.0f / (x))
#endif

// ws layout:
//   [0 .. 2047]          int counts[8][64]
//   [4096 ..]            float4 recs[8][64][SLOTS][2]
//                        rec = {cx,cy,A,B},{C,bright,_,_};  t = A dx^2+B dx dy+C dy^2 (log2)
// Total: 4096 + 8*64*228*32 B = 3.74 MB  (ws is ~268 MB)

// ---------------- Kernel A: per-electrode precompute + per-tile compaction --------------
// grid (8 tilegroups, 8 batches) x 256 threads. Each block: compute 225 records
// in registers (HW trig/rcp), then for its 8 tiles ballot-compact survivors into ws.
extern "C" __global__ void __launch_bounds__(256)
mvg_prep(const float* __restrict__ stim, const float* __restrict__ params,
         const float* __restrict__ elec_x, const float* __restrict__ elec_y,
         const float* __restrict__ slopes, int* __restrict__ counts,
         float4* __restrict__ recs)
{
    const int b    = blockIdx.y;
    const int tg   = blockIdx.x;          // tiles tg*8 .. tg*8+7
    const int tid  = threadIdx.x;
    const int lane = tid & 63;
    const int wv   = tid >> 6;

    __shared__ int scnt8[8];
    __shared__ int wbase[4];
    if (tid < 8) scnt8[tid] = 0;
    __syncthreads();

    float cx = 0.f, cy = 0.f, A = 0.f, B = 0.f, C = 0.f, R = -1e9f, bright = 0.f;
    const bool has = tid < Ee;
    if (has) {
        const float* p = params + b * 13;
        const float rho = p[0], lam = p[1], osc = p[2];
        const float pa0 = p[3], pa1 = p[4], pa2 = p[5], pa3 = p[6], pa4 = p[7];
        const float impx = p[8], impy = p[9], rot = p[10], locx = p[11];

        const float cr = COSR(rot), sr = SINR(rot);
        const float exl = elec_x[tid], eyl = elec_y[tid];
        const float exv = exl * cr - eyl * sr + impx;
        const float eyv = exl * sr + eyl * cr + impy;

        const float offx = locx - ODXc;
        const float qx = (exv - offx - XLOWc) * RSTEP;
        const float qy = (eyv - XLOWc) * RSTEP;
        const float fx = fminf(fmaxf(floorf(qx), 0.0f), (float)(NPI - 2));
        const float fy = fminf(fmaxf(floorf(qy), 0.0f), (float)(NPI - 2));
        const int ix = (int)fx, iy = (int)fy;
        const float ax = fminf(fmaxf(qx - fx, 0.0f), 1.0f);
        const float ay = fminf(fmaxf(qy - fy, 0.0f), 1.0f);
        const float g00 = slopes[iy * NPI + ix];
        const float g01 = slopes[iy * NPI + ix + 1];
        const float g10 = slopes[(iy + 1) * NPI + ix];
        const float g11 = slopes[(iy + 1) * NPI + ix + 1];
        const float top = g00 + ax * (g01 - g00);
        const float bot = g10 + ax * (g11 - g10);
        float th = top + ay * (bot - top);
        th = (th < -0.5f * PIc) ? th + PIc : th;
        th *= osc;

        const float* st = stim + (b * Ee + tid) * 3;
        const float freq = st[0], amp = st[1], pdur = st[2];

        const float rho_s = fmaxf(rho * amp * pa3, 1.0f);
        float lam_s = lam * EXP2F(pa4 * (LOG2F(pdur) + NL2_045));
        lam_s = fminf(fmaxf(lam_s, 0.0f), 0.99f);
        bright = (amp > 0.25f)
                   ? (pa0 * EXP2F(pa1 * LOG2F(fmaxf(amp, 1e-5f))) + pa2 * freq)
                   : 0.0f;

        const float temp2 = sqrtf(1.0f - lam_s * lam_s);
        const float rt2  = RCPF(temp2);
        const float sy_ = rho_s * INV4PI * rt2;
        const float sx_ = rho_s * temp2 * INV4PI;
        const float s = SINR(th), c = COSR(th);
        const float cov00 = sx_ * c * c + sy_ * s * s;
        const float cov01 = (sx_ - sy_) * s * c;
        const float cov11 = sx_ * s * s + sy_ * c * c;
        const float det  = cov00 * cov11 - cov01 * cov01;
        const float rdet = RCPF(det);
        const float i00 =  cov11 * rdet;
        const float i01 = -cov01 * rdet;
        const float i11 =  cov00 * rdet;

        cx = exv * (1.0f / 70.0f) + 60.0f;   // (x/280+15)*4
        cy = 61.0f - eyv * (1.0f / 70.0f);   // 121 - (y/280+15)*4

        A = i00 * NHL;
        B = i01 * 2.0f * NHL;
        C = i11 * NHL;

        const float a = -A, bq = -B, cc = -C;
        const float lam_min = 0.5f * ((a + cc) - sqrtf((a - cc) * (a - cc) + bq * bq));
        if (bright != 0.0f && lam_min > 0.0f)      R = sqrtf(CULL_T / lam_min) + 0.5f;
        else if (bright != 0.0f)                   R = 1e9f;
        else                                       R = -1e9f;
    }

    // per-tile ballot compaction
    for (int t = 0; t < 8; ++t) {
        const int tile = tg * 8 + t;
        const int tx = tile & (XT - 1), ty = tile >> 3;
        const float pxmin = (float)(tx * TS);
        const float pxmax = (float)min(tx * TS + TS - 1, Ww - 1);
        const float pymax = (float)(Hh - 1 - ty * TS);
        const float pymin = (float)(Hh - 1 - min(ty * TS + TS - 1, Hh - 1));

        const bool live = has &&
            (cx + R >= pxmin) && (cx - R <= pxmax) &&
            (cy + R >= pymin) && (cy - R <= pymax);

        const unsigned long long m = __ballot(live);
        const int pre = (int)__popcll(m & ((1ull << lane) - 1ull));
        if (lane == 0) wbase[wv] = atomicAdd(&scnt8[t], (int)__popcll(m));
        const int base = wbase[wv];   // same-wave LDS read-after-write
        if (live) {
            float4* dst = recs + ((size_t)(b * NTILE + tile) * SLOTS + base + pre) * 2;
            dst[0] = make_float4(cx, cy, A, B);
            dst[1] = make_float4(C, bright, 0.0f, 0.0f);
        }
    }
    __syncthreads();

    // counts + zero-padding to multiple of 4 (zero rec contributes bright*exp2 = 0)
    for (int t = 0; t < 8; ++t) {
        const int tile = tg * 8 + t;
        const int n  = scnt8[t];
        const int nr = (n + 3) & ~3;
        if (tid < nr - n) {
            float4* dst = recs + ((size_t)(b * NTILE + tile) * SLOTS + n + tid) * 2;
            dst[0] = make_float4(0.f, 0.f, 0.f, 0.f);
            dst[1] = make_float4(0.f, 0.f, 0.f, 0.f);
        }
        if (tid == 0) counts[b * NTILE + tile] = n;
    }
}

// ---------------- Kernel B: render --------------
// grid (8,8,8) x 256. Stage this tile's pre-compacted list into LDS (<=2
// coalesced float4 loads/thread), then branch-free unroll-4 loop.
extern "C" __global__ void __launch_bounds__(256)
mvg_render(const int* __restrict__ counts, const float4* __restrict__ recs,
           float* __restrict__ out)
{
    __shared__ __align__(16) float4 sL[SLOTS * 2];

    const int b    = blockIdx.z;
    const int tile = blockIdx.y * XT + blockIdx.x;
    const int tid  = threadIdx.x;

    const int n  = counts[b * NTILE + tile];
    const int nr = (n + 3) & ~3;

    const float4* g = recs + (size_t)(b * NTILE + tile) * SLOTS * 2;
    for (int u = tid; u < nr * 2; u += 256) sL[u] = g[u];
    __syncthreads();

    const int lx = tid & (TS - 1);
    const int ly = tid >> 4;
    const int j  = blockIdx.x * TS + lx;
    const int i  = blockIdx.y * TS + ly;
    const float px = (float)j;
    const float py = (float)(Hh - 1 - i);

    float ac0 = 0.f, ac1 = 0.f, ac2 = 0.f, ac3 = 0.f;

#define BODY(k, acc) {                                          \
        const float4 v = sL[2 * (e + (k))];                     \
        const float4 w = sL[2 * (e + (k)) + 1];                 \
        const float dx = px - v.x;                              \
        const float dy = py - v.y;                              \
        const float u_ = fmaf(dx, v.z, dy * v.w);               \
        const float t_ = fmaf(dy * dy, w.x, dx * u_);           \
        acc = fmaf(w.y, EXP2F(t_), acc);                        \
    }

    #pragma unroll 1
    for (int e = 0; e < nr; e += 4) {
        BODY(0, ac0)
        BODY(1, ac1)
        BODY(2, ac2)
        BODY(3, ac3)
    }
#undef BODY

    if (i < Hh && j < Ww)
        out[b * NPIX + i * Ww + j] = (ac0 + ac1) + (ac2 + ac3);
}

extern "C" void kernel_launch(void* const* d_in, const int* in_sizes, int n_in,
                              void* d_out, int out_size, void* d_ws, size_t ws_size,
                              hipStream_t stream) {
    const float* stim   = (const float*)d_in[0];  // (8, 225, 3)
    const float* params = (const float*)d_in[1];  // (8, 13)
    const float* ex     = (const float*)d_in[2];  // (1, 225)
    const float* ey     = (const float*)d_in[3];  // (1, 225)
    const float* slopes = (const float*)d_in[4];  // (200, 200)
    float* out = (float*)d_out;                   // (8, 121, 121) fp32

    int*    counts = (int*)d_ws;
    float4* recs   = (float4*)((char*)d_ws + 4096);

    dim3 gridA(XT, Bb);        // 8 tilegroups x 8 batches
    mvg_prep<<<gridA, 256, 0, stream>>>(stim, params, ex, ey, slopes, counts, recs);

    dim3 gridB(XT, YT, Bb);    // 64 tiles x 8 batches
    mvg_render<<<gridB, 256, 0, stream>>>(counts, recs, out);
}

// Round 5
// 73.332 us; speedup vs baseline: 1.0557x; 1.0557x over previous
//
#include <hip/hip_runtime.h>
#include <math.h>

// Problem constants (match reference)
#define Hh 121
#define Ww 121
#define NPI 200          // N_INTERP
#define Bb 8
#define Ee 225
#define NPIX (Hh * Ww)   // 14641
#define TS 16            // pixel tile side
#define XT 8
#define YT 8
#define MAXC 232         // 225 survivors + pad

#define XLOWc   (-4200.0f)
#define RSTEP   (199.0f / 8400.0f)       // 1/STEP
#define ODXc     4340.0f
#define PIc      3.14159265358979323846f
#define INV2PI   0.15915494309189535f    // v_sin/v_cos take revolutions
#define INV4PI   0.07957747154594767f
#define NHL     (-0.72134752044448170368f)  // -0.5 * log2(e)
#define CULL_T   20.0f   // drop terms provably < bright * 2^-20
#define NL2_045  1.15200309344504995f    // -log2(0.45)

#if __has_builtin(__builtin_amdgcn_exp2f)
#define EXP2F(x) __builtin_amdgcn_exp2f(x)
#else
#define EXP2F(x) exp2f(x)
#endif
#if __has_builtin(__builtin_amdgcn_logf)
#define LOG2F(x) __builtin_amdgcn_logf(x)
#else
#define LOG2F(x) log2f(x)
#endif
#if __has_builtin(__builtin_amdgcn_sinf)
#define SINR(x) __builtin_amdgcn_sinf((x) * INV2PI)   // sin(x), x radians
#define COSR(x) __builtin_amdgcn_cosf((x) * INV2PI)
#else
#define SINR(x) sinf(x)
#define COSR(x) cosf(x)
#endif
#if __has_builtin(__builtin_amdgcn_rcpf)
#define RCPF(x) __builtin_amdgcn_rcpf(x)
#else
#define RCPF(x) (1.0f / (x))
#endif

// Round 5: single launch, best-of-R3/R4.
//  phase 1 (tid<225): per-(b,e) record in registers using HW trig
//    (v_sin/v_cos, revolutions), v_rcp, exp2/log2 pow identities — no libm.
//  cull vs this block's 16x16 pixel AABB (min-eigenvalue radius, Chebyshev
//    conservative; bright==0 -> always culled).
//  ballot compaction: one LDS atomic per wave (4 total) + __shfl base
//    broadcast; survivors write records straight to LDS.
//  zero-pad to multiple of 4 (zero rec contributes bright*exp2(0)=0), then
//  branch-free unroll-4 render loop (8 independent broadcast LDS reads in
//  flight -> ILP hides LDS latency at 2 blocks/CU occupancy).
extern "C" __global__ void __launch_bounds__(256)
mvg_fused(const float* __restrict__ stim, const float* __restrict__ params,
          const float* __restrict__ elec_x, const float* __restrict__ elec_y,
          const float* __restrict__ slopes, float* __restrict__ out)
{
    __shared__ __align__(16) float4 scA[MAXC];  // {cx, cy, A, B}
    __shared__ __align__(8)  float2 scB[MAXC];  // {C, bright}
    __shared__ int scnt;

    const int b    = blockIdx.z;
    const int tid  = threadIdx.x;
    const int lane = tid & 63;

    if (tid == 0) scnt = 0;
    __syncthreads();

    // Block pixel AABB
    const int   jmin = blockIdx.x * TS;
    const int   jmax = min(jmin + TS - 1, Ww - 1);
    const int   imin = blockIdx.y * TS;
    const int   imax = min(imin + TS - 1, Hh - 1);
    const float pxminf = (float)jmin, pxmaxf = (float)jmax;
    const float pyminf = (float)(Hh - 1 - imax), pymaxf = (float)(Hh - 1 - imin);

    float cx = 0.f, cy = 0.f, A = 0.f, B = 0.f, C = 0.f, bright = 0.f, R = -1e9f;
    const bool has = tid < Ee;
    if (has) {
        const float* p = params + b * 13;
        const float rho = p[0], lam = p[1], osc = p[2];
        const float pa0 = p[3], pa1 = p[4], pa2 = p[5], pa3 = p[6], pa4 = p[7];
        const float impx = p[8], impy = p[9], rot = p[10], locx = p[11];

        const float cr = COSR(rot), sr = SINR(rot);
        const float exl = elec_x[tid], eyl = elec_y[tid];
        const float exv = exl * cr - eyl * sr + impx;
        const float eyv = exl * sr + eyl * cr + impy;

        // bilinear interp of slopes
        const float offx = locx - ODXc;
        const float qx = (exv - offx - XLOWc) * RSTEP;
        const float qy = (eyv - XLOWc) * RSTEP;
        const float fx = fminf(fmaxf(floorf(qx), 0.0f), (float)(NPI - 2));
        const float fy = fminf(fmaxf(floorf(qy), 0.0f), (float)(NPI - 2));
        const int ix = (int)fx, iy = (int)fy;
        const float ax = fminf(fmaxf(qx - fx, 0.0f), 1.0f);
        const float ay = fminf(fmaxf(qy - fy, 0.0f), 1.0f);
        const float g00 = slopes[iy * NPI + ix];
        const float g01 = slopes[iy * NPI + ix + 1];
        const float g10 = slopes[(iy + 1) * NPI + ix];
        const float g11 = slopes[(iy + 1) * NPI + ix + 1];
        const float top = g00 + ax * (g01 - g00);
        const float bot = g10 + ax * (g11 - g10);
        float th = top + ay * (bot - top);
        th = (th < -0.5f * PIc) ? th + PIc : th;
        th *= osc;

        const float* st = stim + (b * Ee + tid) * 3;
        const float freq = st[0], amp = st[1], pdur = st[2];

        const float rho_s = fmaxf(rho * amp * pa3, 1.0f);
        float lam_s = lam * EXP2F(pa4 * (LOG2F(pdur) + NL2_045));
        lam_s = fminf(fmaxf(lam_s, 0.0f), 0.99f);
        bright = (amp > 0.25f)
                   ? (pa0 * EXP2F(pa1 * LOG2F(fmaxf(amp, 1e-5f))) + pa2 * freq)
                   : 0.0f;

        const float temp2 = sqrtf(1.0f - lam_s * lam_s);
        const float sy_ = rho_s * INV4PI * RCPF(temp2);
        const float sx_ = rho_s * temp2 * INV4PI;
        const float s = SINR(th), c = COSR(th);
        const float cov00 = sx_ * c * c + sy_ * s * s;
        const float cov01 = (sx_ - sy_) * s * c;
        const float cov11 = sx_ * s * s + sy_ * c * c;
        const float det  = cov00 * cov11 - cov01 * cov01;
        const float rdet = RCPF(det);
        const float i00 =  cov11 * rdet;
        const float i01 = -cov01 * rdet;
        const float i11 =  cov00 * rdet;

        cx = exv * (1.0f / 70.0f) + 60.0f;   // (x/280+15)*4
        cy = 61.0f - eyv * (1.0f / 70.0f);   // 121 - (y/280+15)*4

        A = i00 * NHL;
        B = i01 * 2.0f * NHL;
        C = i11 * NHL;

        const float a = -A, bq = -B, cc = -C;
        const float lam_min = 0.5f * ((a + cc) - sqrtf((a - cc) * (a - cc) + bq * bq));
        if (bright != 0.0f && lam_min > 0.0f)      R = sqrtf(CULL_T / lam_min) + 0.5f;
        else if (bright != 0.0f)                   R = 1e9f;
    }

    const bool live = has &&
        (cx + R >= pxminf) && (cx - R <= pxmaxf) &&
        (cy + R >= pyminf) && (cy - R <= pymaxf);

    // ballot compaction: 1 LDS atomic per wave, base broadcast via shfl
    {
        const unsigned long long m = __ballot(live);
        const int pre   = (int)__popcll(m & ((1ull << lane) - 1ull));
        const int wvcnt = (int)__popcll(m);
        int b0 = 0;
        if (lane == 0 && wvcnt) b0 = atomicAdd(&scnt, wvcnt);
        const int base = __shfl(b0, 0);
        if (live) {
            const int pos = base + pre;
            scA[pos] = make_float4(cx, cy, A, B);
            scB[pos] = make_float2(C, bright);
        }
    }
    __syncthreads();

    const int cnt = scnt;
    if (tid < 4) {
        scA[cnt + tid] = make_float4(0.f, 0.f, 0.f, 0.f);
        scB[cnt + tid] = make_float2(0.f, 0.f);
    }
    __syncthreads();
    const int n = (cnt + 3) & ~3;

    // thread -> pixel of this tile
    const int lx = tid & (TS - 1);
    const int ly = tid >> 4;
    const int j  = jmin + lx;
    const int i  = imin + ly;
    const float px = (float)j;
    const float py = (float)(Hh - 1 - i);

    float ac0 = 0.f, ac1 = 0.f, ac2 = 0.f, ac3 = 0.f;

#define BODY(k, acc) {                                          \
        const float4 v = scA[e + (k)];                          \
        const float2 w = scB[e + (k)];                          \
        const float dx = px - v.x;                              \
        const float dy = py - v.y;                              \
        const float u_ = fmaf(dx, v.z, dy * v.w);               \
        const float t_ = fmaf(dy * dy, w.x, dx * u_);           \
        acc = fmaf(w.y, EXP2F(t_), acc);                        \
    }

    #pragma unroll 1
    for (int e = 0; e < n; e += 4) {
        BODY(0, ac0)
        BODY(1, ac1)
        BODY(2, ac2)
        BODY(3, ac3)
    }
#undef BODY

    if (i < Hh && j < Ww)
        out[b * NPIX + i * Ww + j] = (ac0 + ac1) + (ac2 + ac3);
}

extern "C" void kernel_launch(void* const* d_in, const int* in_sizes, int n_in,
                              void* d_out, int out_size, void* d_ws, size_t ws_size,
                              hipStream_t stream) {
    const float* stim   = (const float*)d_in[0];  // (8, 225, 3)
    const float* params = (const float*)d_in[1];  // (8, 13)
    const float* ex     = (const float*)d_in[2];  // (1, 225)
    const float* ey     = (const float*)d_in[3];  // (1, 225)
    const float* slopes = (const float*)d_in[4];  // (200, 200)
    // d_in[5] = pixelgrid: unused, indices derived analytically
    float* out = (float*)d_out;                   // (8, 121, 121) fp32

    dim3 grid(XT, YT, Bb);  // 8x8 tiles x 8 batches = 512 blocks, one launch
    mvg_fused<<<grid, 256, 0, stream>>>(stim, params, ex, ey, slopes, out);
}